// Round 4
// baseline (134.010 us; speedup 1.0000x reference)
//
#include <hip/hip_runtime.h>
#include <hip/hip_bf16.h>
#include <cstddef>

#define NAGENT 8
#define DIN    128
#define HID    64
#define NACT   16

typedef __attribute__((ext_vector_type(8))) short bf16x8;
typedef __attribute__((ext_vector_type(4))) float f32x4;

__device__ __forceinline__ short f2bf(float f) {
    __hip_bfloat16 h = __float2bfloat16(f);      // RNE; compiler packs pairs to v_cvt_pk_bf16_f32
    union { __hip_bfloat16 h; short s; } u; u.h = h;
    return u.s;
}
__device__ __forceinline__ float sigmoid_f(float v) { return 1.0f / (1.0f + __expf(-v)); }
__device__ __forceinline__ float tanh_f(float v) {
    v = fminf(fmaxf(v, -15.0f), 15.0f);
    float e = __expf(2.0f * v);
    return (e - 1.0f) / (e + 1.0f);
}
__device__ __forceinline__ bf16x8 cvt8pair(float4 v0, float4 v1) {
    bf16x8 r;
    r[0] = f2bf(v0.x); r[1] = f2bf(v0.y); r[2] = f2bf(v0.z); r[3] = f2bf(v0.w);
    r[4] = f2bf(v1.x); r[5] = f2bf(v1.y); r[6] = f2bf(v1.z); r[7] = f2bf(v1.w);
    return r;
}
__device__ __forceinline__ void gload_lds16(const void* g, void* l) {
    __builtin_amdgcn_global_load_lds(
        (const __attribute__((address_space(1))) unsigned int*)g,
        (__attribute__((address_space(3))) unsigned int*)l, 16, 0, 0);
}

// ---------------- weight fp32 -> bf16 fragment-major packing ----------------
// Per-agent packed layout (shorts), base a*33792:
//   W1  chunks c in [0,1024):    c = (n*4+k)*64 + lane      -> W1[a][n*16+lr][k*32+lk*8 ..+8]
//   Wih chunks c in [1024,2560): c-1024 = ((g*4+n)*2+kk)*64+lane -> Wih[a][g*64+n*16+lr][kk*32+lk*8..]
//   Whh chunks c in [2560,4096): same with Whh
//   W2  chunks c in [4096,4224): c-4096 = kk*64+lane        -> W2[a][lr][kk*32+lk*8..]
extern "C" __global__ void __launch_bounds__(256)
conv_weights_packed(const float* __restrict__ W1, const float* __restrict__ Wih,
                    const float* __restrict__ Whh, const float* __restrict__ W2,
                    short* __restrict__ ws)
{
    const int a = blockIdx.y;
    const int c = blockIdx.x * 256 + threadIdx.x;
    if (c >= 4224) return;
    const int lane = c & 63, lr = lane & 15, lk = lane >> 4;
    const float* src;
    if (c < 1024) {
        int n = c >> 8, k = (c >> 6) & 3;
        src = W1 + a * 8192 + (n * 16 + lr) * 128 + k * 32 + lk * 8;
    } else if (c < 2560) {
        int idx = (c - 1024) >> 6;
        int g = idx >> 3, n = (idx >> 1) & 3, kk = idx & 1;
        src = Wih + a * 12288 + (g * 64 + n * 16 + lr) * 64 + kk * 32 + lk * 8;
    } else if (c < 4096) {
        int idx = (c - 2560) >> 6;
        int g = idx >> 3, n = (idx >> 1) & 3, kk = idx & 1;
        src = Whh + a * 12288 + (g * 64 + n * 16 + lr) * 64 + kk * 32 + lk * 8;
    } else {
        int kk = (c - 4096) >> 6;
        src = W2 + a * 1024 + lr * 64 + kk * 32 + lk * 8;
    }
    float4 v0 = ((const float4*)src)[0];
    float4 v1 = ((const float4*)src)[1];
    bf16x8 o = cvt8pair(v0, v1);
    *(bf16x8*)(ws + (size_t)a * 33792 + (size_t)c * 8) = o;
}

// ---------------- main fused kernel ----------------
// grid (B/512, A), 1024 threads (16 waves), 1 block/CU, 4 waves/SIMD.
// Block stages agent weights (66KB) to LDS once; each wave processes 2
// row-tiles of 16 with 1-tile-ahead x/h register prefetch. No inter-wave sync
// after staging.
extern "C" __global__ void __launch_bounds__(1024)
rnn_main(const float* __restrict__ x,     // [B*A, D]
         const float* __restrict__ hin,   // [B, A, H]
         const float* __restrict__ b1, const float* __restrict__ bih,
         const float* __restrict__ bhh, const float* __restrict__ b2,
         const short* __restrict__ wsp,   // packed bf16 weights
         float* __restrict__ qout,        // [B*A, NACT]
         float* __restrict__ hout)        // [B, A, H]
{
    const int a    = blockIdx.y;
    const int bx   = blockIdx.x;
    const int t    = threadIdx.x;
    const int wid  = t >> 6;              // 0..15
    const int lane = t & 63;
    const int lr   = lane & 15;
    const int lk   = lane >> 4;

    __shared__ short wlds[33792];           // 66 KB packed weights
    __shared__ short zs[16 * 16 * 64];      // per-wave 2KB transpose buffers (32 KB)
    char* zb = (char*)(zs + wid * 16 * 64);

    // ---- stage weights: 66 rounds x 1KB, split across 16 waves ----
    const short* wsA = wsp + (size_t)a * 33792;
    for (int r = wid; r < 66; r += 16)
        gload_lds16(wsA + (size_t)r * 512 + lane * 8, wlds + r * 512);

    // ---- hoist biases (tile-invariant, per-lane) ----
    float b1v[4], biv[12], bhv[12];
    #pragma unroll
    for (int n = 0; n < 4; ++n) b1v[n] = b1[a * HID + n * 16 + lr];
    #pragma unroll
    for (int g = 0; g < 3; ++g)
        #pragma unroll
        for (int n = 0; n < 4; ++n) {
            biv[g * 4 + n] = bih[a * 3 * HID + g * HID + n * 16 + lr];
            bhv[g * 4 + n] = bhh[a * 3 * HID + g * HID + n * 16 + lr];
        }
    float bqv = b2[a * NACT + lr];

    __syncthreads();   // weights staged (drains vmcnt)

    const int tile0 = bx * 32 + wid * 2;

    float4 curx[8], curh[4], nxtx[8], nxth[4];

    auto load_tile = [&](int tile, float4* xr, float4* hr) {
        const int arow = tile * 16 + lr;
        const float* xrow = x + ((size_t)arow * NAGENT + a) * DIN + lk * 8;
        const float* hrow = hin + ((size_t)arow * NAGENT + a) * HID + lk * 8;
        #pragma unroll
        for (int k = 0; k < 4; ++k) {
            xr[2 * k]     = *(const float4*)(xrow + k * 32);
            xr[2 * k + 1] = *(const float4*)(xrow + k * 32 + 4);
        }
        #pragma unroll
        for (int kk = 0; kk < 2; ++kk) {
            hr[2 * kk]     = *(const float4*)(hrow + kk * 32);
            hr[2 * kk + 1] = *(const float4*)(hrow + kk * 32 + 4);
        }
    };

    auto compute = [&](int tile, const float4* xr, const float4* hr) {
        bf16x8 xf[4], hf[2];
        #pragma unroll
        for (int k = 0; k < 4; ++k) xf[k] = cvt8pair(xr[2 * k], xr[2 * k + 1]);
        #pragma unroll
        for (int kk = 0; kk < 2; ++kk) hf[kk] = cvt8pair(hr[2 * kk], hr[2 * kk + 1]);

        // ---- fc1 ----
        f32x4 acc1[4];
        #pragma unroll
        for (int n = 0; n < 4; ++n) acc1[n] = (f32x4){b1v[n], b1v[n], b1v[n], b1v[n]};
        #pragma unroll
        for (int k = 0; k < 4; ++k)
            #pragma unroll
            for (int n = 0; n < 4; ++n) {
                bf16x8 wb = *(const bf16x8*)(wlds + ((n * 4 + k) * 64 + lane) * 8);
                acc1[n] = __builtin_amdgcn_mfma_f32_16x16x32_bf16(xf[k], wb, acc1[n], 0, 0, 0);
            }
        #pragma unroll
        for (int n = 0; n < 4; ++n)
            #pragma unroll
            for (int j = 0; j < 4; ++j) {
                int row = lk * 4 + j, col = n * 16 + lr;
                *(short*)(zb + row * 128 + ((col * 2) ^ ((row & 7) << 4))) =
                    f2bf(fmaxf(acc1[n][j], 0.0f));
            }

        // ---- GRU gates ----
        float rg[16], zg[16];
        #pragma unroll
        for (int g = 0; g < 3; ++g) {
            f32x4 aI[4], aH[4];
            #pragma unroll
            for (int n = 0; n < 4; ++n) {
                float bi = biv[g * 4 + n], bh = bhv[g * 4 + n];
                aI[n] = (f32x4){bi, bi, bi, bi};
                aH[n] = (f32x4){bh, bh, bh, bh};
            }
            #pragma unroll
            for (int kk = 0; kk < 2; ++kk) {
                bf16x8 za = *(const bf16x8*)(zb + lr * 128 +
                                             ((kk * 64 + lk * 16) ^ ((lr & 7) << 4)));
                #pragma unroll
                for (int n = 0; n < 4; ++n) {
                    bf16x8 wi = *(const bf16x8*)(wlds + 8192 +
                                  (((g * 4 + n) * 2 + kk) * 64 + lane) * 8);
                    bf16x8 wh = *(const bf16x8*)(wlds + 20480 +
                                  (((g * 4 + n) * 2 + kk) * 64 + lane) * 8);
                    aI[n] = __builtin_amdgcn_mfma_f32_16x16x32_bf16(za, wi, aI[n], 0, 0, 0);
                    aH[n] = __builtin_amdgcn_mfma_f32_16x16x32_bf16(hf[kk], wh, aH[n], 0, 0, 0);
                }
            }
            if (g == 0) {
                #pragma unroll
                for (int n = 0; n < 4; ++n)
                    #pragma unroll
                    for (int j = 0; j < 4; ++j)
                        rg[n * 4 + j] = sigmoid_f(aI[n][j] + aH[n][j]);
            } else if (g == 1) {
                #pragma unroll
                for (int n = 0; n < 4; ++n)
                    #pragma unroll
                    for (int j = 0; j < 4; ++j)
                        zg[n * 4 + j] = sigmoid_f(aI[n][j] + aH[n][j]);
            } else {
                #pragma unroll
                for (int n = 0; n < 4; ++n)
                    #pragma unroll
                    for (int j = 0; j < 4; ++j) {
                        int row = lk * 4 + j, col = n * 16 + lr;
                        float nn = tanh_f(aI[n][j] + rg[n * 4 + j] * aH[n][j]);
                        float hp = hin[((size_t)(tile * 16 + row) * NAGENT + a) * HID + col];
                        float zv = zg[n * 4 + j];
                        float hv = (1.0f - zv) * nn + zv * hp;
                        hout[((size_t)(tile * 16 + row) * NAGENT + a) * HID + col] = hv;
                        *(short*)(zb + row * 128 + ((col * 2) ^ ((row & 7) << 4))) = f2bf(hv);
                    }
            }
        }

        // ---- fc2 ----
        f32x4 q = (f32x4){bqv, bqv, bqv, bqv};
        #pragma unroll
        for (int kk = 0; kk < 2; ++kk) {
            bf16x8 ha = *(const bf16x8*)(zb + lr * 128 +
                                         ((kk * 64 + lk * 16) ^ ((lr & 7) << 4)));
            bf16x8 wb = *(const bf16x8*)(wlds + 32768 + (kk * 64 + lane) * 8);
            q = __builtin_amdgcn_mfma_f32_16x16x32_bf16(ha, wb, q, 0, 0, 0);
        }
        #pragma unroll
        for (int j = 0; j < 4; ++j)
            qout[((size_t)(tile * 16 + lk * 4 + j) * NAGENT + a) * NACT + lr] = q[j];
    };

    // ---- pipelined tile loop: prefetch next tile during compute ----
    load_tile(tile0, curx, curh);
    #pragma unroll
    for (int i = 0; i < 2; ++i) {
        if (i < 1) load_tile(tile0 + i + 1, nxtx, nxth);
        compute(tile0 + i, curx, curh);
        if (i < 1) {
            #pragma unroll
            for (int u = 0; u < 8; ++u) curx[u] = nxtx[u];
            #pragma unroll
            for (int u = 0; u < 4; ++u) curh[u] = nxth[u];
        }
    }
}

extern "C" void kernel_launch(void* const* d_in, const int* in_sizes, int n_in,
                              void* d_out, int out_size, void* d_ws, size_t ws_size,
                              hipStream_t stream)
{
    const float* x   = (const float*)d_in[0];
    const float* hin = (const float*)d_in[1];
    const float* W1  = (const float*)d_in[2];
    const float* b1  = (const float*)d_in[3];
    const float* Wih = (const float*)d_in[4];
    const float* bih = (const float*)d_in[5];
    const float* Whh = (const float*)d_in[6];
    const float* bhh = (const float*)d_in[7];
    const float* W2  = (const float*)d_in[8];
    const float* b2  = (const float*)d_in[9];

    const int B = in_sizes[0] / (NAGENT * DIN);   // 16384

    float* qout = (float*)d_out;                              // [B*A, NACT]
    float* hout = (float*)d_out + (size_t)B * NAGENT * NACT;  // [B, A, H]

    short* wsp = (short*)d_ws;                                // 540,672 B packed

    conv_weights_packed<<<dim3(17, NAGENT), 256, 0, stream>>>(W1, Wih, Whh, W2, wsp);

    dim3 grid(B / 512, NAGENT);
    rnn_main<<<grid, 1024, 0, stream>>>(x, hin, b1, bih, bhh, b2, wsp, qout, hout);
}